// Round 8
// baseline (80.823 us; speedup 1.0000x reference)
//
#include <hip/hip_runtime.h>

// out[(i*7+k)*C + c] = bias[(i*7+k)*C + c] + sum_j x[c*49 + j*7 + i] * weight[(j*7+k)*C + c]
//
// Memory-bound fp32, ~402 MB logical. R4/R7 plateau at 72-73 us but with HBM
// at only 3.5 TB/s (56%) and occupancy 46% (= 2 resident blocks: 50 KiB LDS
// rounds up past the 3-block mark) -> still concurrency-limited.
// R8: CHB=128, thread owns a channel PAIR (f2, 8 B/lane), LDS 25 KiB ->
// 4 blocks x 7 waves = 28/32 waves (87.5%) even with coarse LDS granularity.
// Same structure otherwise: transposed swizzled LDS, w-hoist, 1-deep
// b-prefetch, nontemporal stores.
//
// Swizzle (f2-slot granularity, g = pos&31):
//   element (cl,pos) lives at dword pos*128 + (((cl>>1)^g)<<1 | (cl&1)).
//   Read: lane q reads slot q^g -> permutation of a contiguous 512B row,
//   conflict-free. Write: same-cl lane runs step pos by 2 -> slot hops
//   spread banks (<=4-way on the 28-write staging path only).

typedef float f4 __attribute__((ext_vector_type(4)));
typedef float f2 __attribute__((ext_vector_type(2)));

constexpr int C    = 524288;
constexpr int HW   = 49;
constexpr int CHB  = 128;              // channels per block
constexpr int NTHR = 64 * 7;           // 448 threads = 7 waves
constexpr int RS   = CHB;              // LDS row stride (dwords) per pos
constexpr int NF2  = CHB * HW / 2;     // 3136 f2 per block slab

__global__ __launch_bounds__(NTHR, 7)
void mylinear_kernel(const float* __restrict__ x,
                     const float* __restrict__ w,
                     const float* __restrict__ b,
                     float* __restrict__ out) {
    __shared__ float xs[HW * CHB];     // 25088 B

    const int tid   = threadIdx.y * 64 + threadIdx.x;
    const int cbase = blockIdx.x * CHB;

    // ---- stage x slab (f2, 512B/wave/instr), transpose + swizzle into LDS ----
    const f2* __restrict__ xsrc = reinterpret_cast<const f2*>(x + (size_t)cbase * HW);
#pragma unroll
    for (int it = 0; it < NF2 / NTHR; ++it) {   // 3136/448 = 7 exact
        const int idx = it * NTHR + tid;
        const f2 v = xsrc[idx];
#pragma unroll
        for (int t = 0; t < 2; ++t) {
            const int e   = idx * 2 + t;
            const int cl  = e / HW;            // local channel 0..127
            const int pos = e % HW;            // 0..48
            const int sl  = (cl >> 1) ^ (pos & 31);
            xs[pos * RS + (sl << 1 | (cl & 1))] = v[t];
        }
    }
    __syncthreads();

    // ---- compute: thread (q, kk) -> channels cbase+2q, 2q+1, outputs p=i*7+kk ----
    const int q  = threadIdx.x;                // pair index 0..63
    const int kk = threadIdx.y;                // 0..6
    const int c  = cbase + (q << 1);

    f2 wq[7];
#pragma unroll
    for (int j = 0; j < 7; ++j)
        wq[j] = *reinterpret_cast<const f2*>(w + (size_t)(j * 7 + kk) * C + c);

    f2 bcur = *reinterpret_cast<const f2*>(b + (size_t)kk * C + c);

#pragma unroll
    for (int i = 0; i < 7; ++i) {
        f2 bnext;
        if (i < 6)
            bnext = *reinterpret_cast<const f2*>(b + (size_t)((i + 1) * 7 + kk) * C + c);

        f2 xv[7];
#pragma unroll
        for (int j = 0; j < 7; ++j) {
            const int pos = j * 7 + i;
            const int sl  = q ^ (pos & 31);
            xv[j] = *reinterpret_cast<const f2*>(xs + pos * RS + (sl << 1));
        }
        f2 acc = bcur;
#pragma unroll
        for (int j = 0; j < 7; ++j) {
            acc.x = fmaf(xv[j].x, wq[j].x, acc.x);
            acc.y = fmaf(xv[j].y, wq[j].y, acc.y);
        }
        __builtin_nontemporal_store(acc,
            reinterpret_cast<f2*>(out + (size_t)(i * 7 + kk) * C + c));
        bcur = bnext;
    }
}

extern "C" void kernel_launch(void* const* d_in, const int* in_sizes, int n_in,
                              void* d_out, int out_size, void* d_ws, size_t ws_size,
                              hipStream_t stream) {
    const float* x = (const float*)d_in[0];
    const float* w = (const float*)d_in[1];
    const float* b = (const float*)d_in[2];
    float* out     = (float*)d_out;

    dim3 grid(C / CHB), block(64, 7);
    mylinear_kernel<<<grid, block, 0, stream>>>(x, w, b, out);
}